// Round 1
// baseline (6909.122 us; speedup 1.0000x reference)
//
#include <hip/hip_runtime.h>
#include <hip/hip_bf16.h>

// Problem constants
#define BATCH 2
#define SEQ   2048
#define EMB   1024
#define NH    16
#define HD    64          // head dim
#define QKV_LD (3*EMB)    // 3072, row stride of qkv buffer

// ---------------------------------------------------------------------------
// Tiled fp32 GEMM with bias: C[M,N] = A[M,K] @ B[K,N] + bias[N]
// 64x64 tile, BK=16, 256 threads, 4x4 per-thread microtile.
// Assumes M%64==0, N%64==0, K%16==0 (true for all our shapes).
// ---------------------------------------------------------------------------
#define TILE 64
#define BK   16

__global__ __launch_bounds__(256)
void gemm_bias(const float* __restrict__ A, const float* __restrict__ B,
               const float* __restrict__ bias, float* __restrict__ C,
               int M, int N, int K) {
    __shared__ float As[BK][TILE + 1];
    __shared__ float Bs[BK][TILE + 1];

    const int tid = threadIdx.x;           // 0..255
    const int tx  = tid & 15;              // 0..15 (cols)
    const int ty  = tid >> 4;              // 0..15 (rows)
    const int row0 = blockIdx.y * TILE;
    const int col0 = blockIdx.x * TILE;

    float acc[4][4];
#pragma unroll
    for (int i = 0; i < 4; ++i)
#pragma unroll
        for (int j = 0; j < 4; ++j) acc[i][j] = 0.f;

    for (int k0 = 0; k0 < K; k0 += BK) {
        // Load A tile (64 rows x 16 k) -> As[k][m]
#pragma unroll
        for (int t = tid; t < TILE * BK; t += 256) {
            int m = t >> 4;            // t / BK
            int k = t & (BK - 1);      // t % BK
            As[k][m] = A[(size_t)(row0 + m) * K + k0 + k];
        }
        // Load B tile (16 k x 64 n) -> Bs[k][n], coalesced over n
#pragma unroll
        for (int t = tid; t < BK * TILE; t += 256) {
            int k = t >> 6;            // t / 64
            int n = t & 63;            // t % 64
            Bs[k][n] = B[(size_t)(k0 + k) * N + col0 + n];
        }
        __syncthreads();

#pragma unroll
        for (int k = 0; k < BK; ++k) {
            float a[4], b[4];
#pragma unroll
            for (int i = 0; i < 4; ++i) a[i] = As[k][ty * 4 + i];
#pragma unroll
            for (int j = 0; j < 4; ++j) b[j] = Bs[k][tx * 4 + j];
#pragma unroll
            for (int i = 0; i < 4; ++i)
#pragma unroll
                for (int j = 0; j < 4; ++j) acc[i][j] += a[i] * b[j];
        }
        __syncthreads();
    }

#pragma unroll
    for (int i = 0; i < 4; ++i) {
        int r = row0 + ty * 4 + i;
#pragma unroll
        for (int j = 0; j < 4; ++j) {
            int c = col0 + tx * 4 + j;
            C[(size_t)r * N + c] = acc[i][j] + bias[c];
        }
    }
}

// ---------------------------------------------------------------------------
// Attention: one block (256 threads) per (b, h, i) query row.
// scores -> LDS, block softmax, write attn row (coalesced), PV from LDS probs.
// qkv layout: [B*S, 3*EMB]; within a row, head h occupies [h*192, h*192+192):
//   q at +0, k at +64, v at +128.
// ---------------------------------------------------------------------------
__global__ __launch_bounds__(256)
void attn_kernel(const float* __restrict__ qkv,
                 float* __restrict__ attn,   // [B,H,S,S]
                 float* __restrict__ ctx) {  // [B,S,EMB]
    const int idx = blockIdx.x;
    const int i = idx & (SEQ - 1);
    const int h = (idx >> 11) & (NH - 1);
    const int b = idx >> 15;

    const float* base = qkv + (size_t)b * SEQ * QKV_LD;
    const int hoff = h * (3 * HD);

    __shared__ float qs[HD];
    __shared__ float sc[SEQ];            // 8 KB scores/probs
    __shared__ float redbuf[8];
    __shared__ float pv_part[4][HD];     // PV group partials

    const int tid = threadIdx.x;
    if (tid < HD) qs[tid] = base[(size_t)i * QKV_LD + hoff + tid];
    __syncthreads();

    const float slope = exp2f(-0.5f * (float)(h + 1));

    // ---- scores ----
    float lmax = -3.0e38f;
    for (int j = tid; j < SEQ; j += 256) {
        const float* krow = base + (size_t)j * QKV_LD + hoff + HD;
        float dot = 0.f;
#pragma unroll
        for (int d = 0; d < HD; ++d) dot += qs[d] * krow[d];
        float s = dot * 0.125f + slope * (float)(j - i);
        sc[j] = s;
        lmax = fmaxf(lmax, s);
    }

    // ---- block max ----
#pragma unroll
    for (int off = 32; off > 0; off >>= 1)
        lmax = fmaxf(lmax, __shfl_down(lmax, off));
    const int wave = tid >> 6, lane = tid & 63;
    if (lane == 0) redbuf[wave] = lmax;
    __syncthreads();
    if (tid == 0) {
        float m = redbuf[0];
        for (int w = 1; w < 4; ++w) m = fmaxf(m, redbuf[w]);
        redbuf[4] = m;
    }
    __syncthreads();
    const float rowmax = redbuf[4];

    // ---- exp + sum ----
    float lsum = 0.f;
    for (int j = tid; j < SEQ; j += 256) {
        float e = __expf(sc[j] - rowmax);
        sc[j] = e;
        lsum += e;
    }
#pragma unroll
    for (int off = 32; off > 0; off >>= 1)
        lsum += __shfl_down(lsum, off);
    if (lane == 0) redbuf[wave] = lsum;
    __syncthreads();
    if (tid == 0) {
        float s = redbuf[0] + redbuf[1] + redbuf[2] + redbuf[3];
        redbuf[5] = 1.0f / s;
    }
    __syncthreads();
    const float inv_sum = redbuf[5];

    // ---- normalize + write attn row (coalesced) ----
    float* arow = attn + (size_t)(((size_t)(b * NH + h) * SEQ + i)) * SEQ;
    for (int j = tid; j < SEQ; j += 256) {
        float p = sc[j] * inv_sum;
        sc[j] = p;
        arow[j] = p;
    }
    __syncthreads();

    // ---- PV: threads as (d = tid&63, group = tid>>6); coalesced V reads ----
    const int d = tid & 63;
    const int g = tid >> 6;
    float accv = 0.f;
    const float* vbase = base + hoff + 2 * HD + d;
    for (int j = g * (SEQ / 4); j < (g + 1) * (SEQ / 4); ++j) {
        accv += sc[j] * vbase[(size_t)j * QKV_LD];
    }
    pv_part[g][d] = accv;
    __syncthreads();
    if (tid < HD) {
        float c = pv_part[0][tid] + pv_part[1][tid] + pv_part[2][tid] + pv_part[3][tid];
        ctx[((size_t)(b * SEQ + i)) * EMB + h * HD + tid] = c;
    }
}

// ---------------------------------------------------------------------------

extern "C" void kernel_launch(void* const* d_in, const int* in_sizes, int n_in,
                              void* d_out, int out_size, void* d_ws, size_t ws_size,
                              hipStream_t stream) {
    const float* x    = (const float*)d_in[0];
    const float* Wqkv = (const float*)d_in[1];
    const float* bqkv = (const float*)d_in[2];
    const float* Wout = (const float*)d_in[3];
    const float* bout = (const float*)d_in[4];

    float* out  = (float*)d_out;                                // [B,S,EMB]
    float* attn = out + (size_t)BATCH * SEQ * EMB;              // [B,H,S,S]

    float* qkv = (float*)d_ws;                                  // [B*S, 3*EMB]
    float* ctx = qkv + (size_t)BATCH * SEQ * QKV_LD;            // [B,S,EMB]

    const int M = BATCH * SEQ;   // 4096

    // 1) qkv = x @ Wqkv + bqkv    (M=4096, N=3072, K=1024)
    gemm_bias<<<dim3(QKV_LD / TILE, M / TILE), dim3(256), 0, stream>>>(
        x, Wqkv, bqkv, qkv, M, QKV_LD, EMB);

    // 2) attention (scores+softmax+attn write+PV)
    attn_kernel<<<dim3(BATCH * NH * SEQ), dim3(256), 0, stream>>>(qkv, attn, ctx);

    // 3) out = ctx @ Wout + bout  (M=4096, N=1024, K=1024)
    gemm_bias<<<dim3(EMB / TILE, M / TILE), dim3(256), 0, stream>>>(
        ctx, Wout, bout, out, M, EMB, EMB);
}

// Round 2
// 1595.164 us; speedup vs baseline: 4.3313x; 4.3313x over previous
//
#include <hip/hip_runtime.h>
#include <hip/hip_bf16.h>

// Problem constants
#define BATCH 2
#define SEQ   2048
#define EMB   1024
#define NH    16
#define HD    64

typedef __attribute__((ext_vector_type(8))) short short8;
typedef __attribute__((ext_vector_type(4))) float floatx4;

// fp32 -> bf16 (RNE) as raw ushort bits
__device__ __forceinline__ unsigned short f32_to_bf16(float f) {
    union { float f; unsigned int u; } v; v.f = f;
    unsigned int r = v.u + 0x7fffu + ((v.u >> 16) & 1u);
    return (unsigned short)(r >> 16);
}

// ---------------------------------------------------------------------------
// GEMM1: qkv = x @ Wqkv + bqkv, epilogue scatters bf16 into head-split
// Q/K/V buffers laid out [(b*NH+h)*SEQ + s][HD].
// M=4096, N=3072, K=1024. 64x64 tile, BK=16, 256 threads, 4x4 microtile.
// ---------------------------------------------------------------------------
#define TILE 64
#define BK   16

__global__ __launch_bounds__(256)
void gemm_qkv(const float* __restrict__ A, const float* __restrict__ B,
              const float* __restrict__ bias,
              unsigned short* __restrict__ Qh, unsigned short* __restrict__ Kh,
              unsigned short* __restrict__ Vh) {
    const int N = 3 * EMB, K = EMB;
    __shared__ float As[BK][TILE + 1];
    __shared__ float Bs[BK][TILE + 1];

    const int tid = threadIdx.x;
    const int tx = tid & 15, ty = tid >> 4;
    const int row0 = blockIdx.y * TILE;
    const int col0 = blockIdx.x * TILE;

    float acc[4][4];
#pragma unroll
    for (int i = 0; i < 4; ++i)
#pragma unroll
        for (int j = 0; j < 4; ++j) acc[i][j] = 0.f;

    for (int k0 = 0; k0 < K; k0 += BK) {
#pragma unroll
        for (int t = tid; t < TILE * BK; t += 256) {
            int m = t >> 4, k = t & (BK - 1);
            As[k][m] = A[(size_t)(row0 + m) * K + k0 + k];
        }
#pragma unroll
        for (int t = tid; t < BK * TILE; t += 256) {
            int k = t >> 6, n = t & 63;
            Bs[k][n] = B[(size_t)(k0 + k) * N + col0 + n];
        }
        __syncthreads();
#pragma unroll
        for (int k = 0; k < BK; ++k) {
            float a[4], b[4];
#pragma unroll
            for (int i = 0; i < 4; ++i) a[i] = As[k][ty * 4 + i];
#pragma unroll
            for (int j = 0; j < 4; ++j) b[j] = Bs[k][tx * 4 + j];
#pragma unroll
            for (int i = 0; i < 4; ++i)
#pragma unroll
                for (int j = 0; j < 4; ++j) acc[i][j] += a[i] * b[j];
        }
        __syncthreads();
    }

#pragma unroll
    for (int i = 0; i < 4; ++i) {
        int r = row0 + ty * 4 + i;       // r = b*SEQ + s
        int b = r >> 11, s = r & (SEQ - 1);
#pragma unroll
        for (int j = 0; j < 4; ++j) {
            int c = col0 + tx * 4 + j;   // 0..3071
            int h = c / 192;
            int rem = c - h * 192;
            int which = rem >> 6;        // 0=q 1=k 2=v
            int d = rem & 63;
            unsigned short val = f32_to_bf16(acc[i][j] + bias[c]);
            size_t idx = ((size_t)(b * NH + h) * SEQ + s) * HD + d;
            if (which == 0)      Qh[idx] = val;
            else if (which == 1) Kh[idx] = val;
            else                 Vh[idx] = val;
        }
    }
}

// ---------------------------------------------------------------------------
// GEMM3: out = ctx @ Wout + bout (fp32), M=4096, N=1024, K=1024
// ---------------------------------------------------------------------------
__global__ __launch_bounds__(256)
void gemm_bias(const float* __restrict__ A, const float* __restrict__ B,
               const float* __restrict__ bias, float* __restrict__ C,
               int M, int N, int K) {
    __shared__ float As[BK][TILE + 1];
    __shared__ float Bs[BK][TILE + 1];

    const int tid = threadIdx.x;
    const int tx = tid & 15, ty = tid >> 4;
    const int row0 = blockIdx.y * TILE;
    const int col0 = blockIdx.x * TILE;

    float acc[4][4];
#pragma unroll
    for (int i = 0; i < 4; ++i)
#pragma unroll
        for (int j = 0; j < 4; ++j) acc[i][j] = 0.f;

    for (int k0 = 0; k0 < K; k0 += BK) {
#pragma unroll
        for (int t = tid; t < TILE * BK; t += 256) {
            int m = t >> 4, k = t & (BK - 1);
            As[k][m] = A[(size_t)(row0 + m) * K + k0 + k];
        }
#pragma unroll
        for (int t = tid; t < BK * TILE; t += 256) {
            int k = t >> 6, n = t & 63;
            Bs[k][n] = B[(size_t)(k0 + k) * N + col0 + n];
        }
        __syncthreads();
#pragma unroll
        for (int k = 0; k < BK; ++k) {
            float a[4], b[4];
#pragma unroll
            for (int i = 0; i < 4; ++i) a[i] = As[k][ty * 4 + i];
#pragma unroll
            for (int j = 0; j < 4; ++j) b[j] = Bs[k][tx * 4 + j];
#pragma unroll
            for (int i = 0; i < 4; ++i)
#pragma unroll
                for (int j = 0; j < 4; ++j) acc[i][j] += a[i] * b[j];
        }
        __syncthreads();
    }

#pragma unroll
    for (int i = 0; i < 4; ++i) {
        int r = row0 + ty * 4 + i;
#pragma unroll
        for (int j = 0; j < 4; ++j) {
            int c = col0 + tx * 4 + j;
            C[(size_t)r * N + c] = acc[i][j] + bias[c];
        }
    }
}

// ---------------------------------------------------------------------------
// MFMA flash-style attention, two passes (stats, then recompute+write+PV).
// Block: 256 thr = 4 waves. Block handles 64 query rows of one (b,h).
// Wave w owns query rows [16w, 16w+16).
// mfma_f32_16x16x32_bf16 layouts (m89-verified):
//   A[m=lane&15][k=quad*8+j]   B[k=quad*8+j][n=lane&15]   D: col=lane&15,
//   row=quad*4+reg.
// S = Q*K^T: both frags are 8 contiguous bf16 from row-major [row][d] LDS.
// PV: P via LDS round-trip into A-layout; V staged transposed [d][key].
// ---------------------------------------------------------------------------
#define QT 64
#define KT 64
#define LDST 72   // LDS row stride in ushorts: 144 B (16B-aligned, bank-spread)

__global__ __launch_bounds__(256)
void attn_mfma(const unsigned short* __restrict__ Qh,
               const unsigned short* __restrict__ Kh,
               const unsigned short* __restrict__ Vh,
               float* __restrict__ attn,   // [B,H,S,S]
               float* __restrict__ ctx) {  // [B,S,EMB]
    __shared__ unsigned short qs[QT * LDST];
    __shared__ unsigned short ks[KT * LDST];
    __shared__ unsigned short vt[HD * LDST];
    __shared__ unsigned short ps[4 * 16 * LDST];

    const int tid  = threadIdx.x;
    const int wave = tid >> 6, lane = tid & 63;
    const int quad = lane >> 4, lp = lane & 15;
    const int q0 = blockIdx.x * QT;
    const int bh = blockIdx.y;                 // b*NH + h
    const int h  = bh & (NH - 1);
    const float slope = exp2f(-0.5f * (float)(h + 1));

    const unsigned short* Qbase = Qh + ((size_t)bh * SEQ + q0) * HD;
    const unsigned short* Kbase = Kh + (size_t)bh * SEQ * HD;
    const unsigned short* Vbase = Vh + (size_t)bh * SEQ * HD;

    // ---- stage Q tile (64 x 64 bf16), row-major, stride LDST ----
    for (int c = tid; c < QT * HD / 8; c += 256) {   // 512 chunks of 8 bf16
        int row = c >> 3, seg = c & 7;
        *(uint4*)&qs[row * LDST + seg * 8] =
            *(const uint4*)&Qbase[(size_t)row * HD + seg * 8];
    }
    __syncthreads();

    // Q A-fragments are loop-invariant: hoist.
    const short8 qa0 = *(const short8*)&qs[(16 * wave + lp) * LDST + quad * 8];
    const short8 qa1 = *(const short8*)&qs[(16 * wave + lp) * LDST + 32 + quad * 8];

    const int ig = q0 + 16 * wave + quad * 4;   // +r = global query row

    float m[4], l[4];
#pragma unroll
    for (int r = 0; r < 4; ++r) { m[r] = -1e30f; l[r] = 0.f; }

    // ================= pass 1: online max/sum =================
    for (int kt = 0; kt < SEQ / KT; ++kt) {
        __syncthreads();
        const unsigned short* Ksrc = Kbase + (size_t)kt * KT * HD;
        for (int c = tid; c < KT * HD / 8; c += 256) {
            int row = c >> 3, seg = c & 7;
            *(uint4*)&ks[row * LDST + seg * 8] =
                *(const uint4*)&Ksrc[(size_t)row * HD + seg * 8];
        }
        __syncthreads();

        float sv[4][4];
        float tmax[4] = {-1e30f, -1e30f, -1e30f, -1e30f};
#pragma unroll
        for (int t = 0; t < 4; ++t) {
            short8 b0 = *(const short8*)&ks[(16 * t + lp) * LDST + quad * 8];
            short8 b1 = *(const short8*)&ks[(16 * t + lp) * LDST + 32 + quad * 8];
            floatx4 c = {0.f, 0.f, 0.f, 0.f};
            c = __builtin_amdgcn_mfma_f32_16x16x32_bf16(qa0, b0, c, 0, 0, 0);
            c = __builtin_amdgcn_mfma_f32_16x16x32_bf16(qa1, b1, c, 0, 0, 0);
            int jg = kt * KT + 16 * t + lp;
#pragma unroll
            for (int r = 0; r < 4; ++r) {
                float s = c[r] * 0.125f + slope * (float)(jg - (ig + r));
                sv[t][r] = s;
                tmax[r] = fmaxf(tmax[r], s);
            }
        }
#pragma unroll
        for (int r = 0; r < 4; ++r) {
#pragma unroll
            for (int off = 1; off < 16; off <<= 1)
                tmax[r] = fmaxf(tmax[r], __shfl_xor(tmax[r], off));
            float mn = fmaxf(m[r], tmax[r]);
            float alpha = __expf(m[r] - mn);
            float psum = 0.f;
#pragma unroll
            for (int t = 0; t < 4; ++t) psum += __expf(sv[t][r] - mn);
#pragma unroll
            for (int off = 1; off < 16; off <<= 1)
                psum += __shfl_xor(psum, off);
            l[r] = l[r] * alpha + psum;
            m[r] = mn;
        }
    }

    float invl[4];
#pragma unroll
    for (int r = 0; r < 4; ++r) invl[r] = 1.0f / l[r];

    // ================= pass 2: recompute, write attn, PV =================
    floatx4 o[4];
#pragma unroll
    for (int t = 0; t < 4; ++t) o[t] = (floatx4){0.f, 0.f, 0.f, 0.f};

    float* arow = attn + (size_t)bh * SEQ * SEQ;

    for (int kt = 0; kt < SEQ / KT; ++kt) {
        __syncthreads();
        const unsigned short* Ksrc = Kbase + (size_t)kt * KT * HD;
        const unsigned short* Vsrc = Vbase + (size_t)kt * KT * HD;
        for (int c = tid; c < KT * HD / 8; c += 256) {
            int row = c >> 3, seg = c & 7;
            *(uint4*)&ks[row * LDST + seg * 8] =
                *(const uint4*)&Ksrc[(size_t)row * HD + seg * 8];
            // V: load 8 bf16 of row (key=row), scatter transposed vt[d][key]
            union { uint4 u; unsigned short e[8]; } vv;
            vv.u = *(const uint4*)&Vsrc[(size_t)row * HD + seg * 8];
#pragma unroll
            for (int j = 0; j < 8; ++j)
                vt[(seg * 8 + j) * LDST + row] = vv.e[j];
        }
        __syncthreads();

        float pv[4][4];
#pragma unroll
        for (int t = 0; t < 4; ++t) {
            short8 b0 = *(const short8*)&ks[(16 * t + lp) * LDST + quad * 8];
            short8 b1 = *(const short8*)&ks[(16 * t + lp) * LDST + 32 + quad * 8];
            floatx4 c = {0.f, 0.f, 0.f, 0.f};
            c = __builtin_amdgcn_mfma_f32_16x16x32_bf16(qa0, b0, c, 0, 0, 0);
            c = __builtin_amdgcn_mfma_f32_16x16x32_bf16(qa1, b1, c, 0, 0, 0);
            int jg = kt * KT + 16 * t + lp;
#pragma unroll
            for (int r = 0; r < 4; ++r) {
                float s = c[r] * 0.125f + slope * (float)(jg - (ig + r));
                float p = __expf(s - m[r]) * invl[r];
                pv[t][r] = p;
                arow[(size_t)(ig + r) * SEQ + jg] = p;
            }
        }
        // P -> LDS (bf16, A-layout round trip)
#pragma unroll
        for (int t = 0; t < 4; ++t)
#pragma unroll
            for (int r = 0; r < 4; ++r)
                ps[(wave * 16 + quad * 4 + r) * LDST + 16 * t + lp] =
                    f32_to_bf16(pv[t][r]);
        __syncthreads();

        short8 pa0 = *(const short8*)&ps[(16 * wave + lp) * LDST + quad * 8];
        short8 pa1 = *(const short8*)&ps[(16 * wave + lp) * LDST + 32 + quad * 8];
#pragma unroll
        for (int t = 0; t < 4; ++t) {
            short8 vb0 = *(const short8*)&vt[(16 * t + lp) * LDST + quad * 8];
            short8 vb1 = *(const short8*)&vt[(16 * t + lp) * LDST + 32 + quad * 8];
            o[t] = __builtin_amdgcn_mfma_f32_16x16x32_bf16(pa0, vb0, o[t], 0, 0, 0);
            o[t] = __builtin_amdgcn_mfma_f32_16x16x32_bf16(pa1, vb1, o[t], 0, 0, 0);
        }
    }

    // ---- write ctx ----
    const int b = bh >> 4;
#pragma unroll
    for (int t = 0; t < 4; ++t)
#pragma unroll
        for (int r = 0; r < 4; ++r)
            ctx[((size_t)(b * SEQ + ig + r)) * EMB + h * HD + 16 * t + lp] = o[t][r];
}

// ---------------------------------------------------------------------------

extern "C" void kernel_launch(void* const* d_in, const int* in_sizes, int n_in,
                              void* d_out, int out_size, void* d_ws, size_t ws_size,
                              hipStream_t stream) {
    const float* x    = (const float*)d_in[0];
    const float* Wqkv = (const float*)d_in[1];
    const float* bqkv = (const float*)d_in[2];
    const float* Wout = (const float*)d_in[3];
    const float* bout = (const float*)d_in[4];

    float* out  = (float*)d_out;
    float* attn = out + (size_t)BATCH * SEQ * EMB;

    const size_t HElems = (size_t)BATCH * NH * SEQ * HD;   // 4.19 M
    unsigned short* Qh = (unsigned short*)d_ws;
    unsigned short* Kh = Qh + HElems;
    unsigned short* Vh = Kh + HElems;
    float* ctx = (float*)(Vh + HElems);                    // [B,S,EMB] fp32

    const int M = BATCH * SEQ;  // 4096

    // 1) qkv projection -> bf16 head-split Q/K/V
    gemm_qkv<<<dim3(3 * EMB / TILE, M / TILE), dim3(256), 0, stream>>>(
        x, Wqkv, bqkv, Qh, Kh, Vh);

    // 2) MFMA attention (writes attn + ctx)
    attn_mfma<<<dim3(SEQ / QT, BATCH * NH), dim3(256), 0, stream>>>(
        Qh, Kh, Vh, attn, ctx);

    // 3) out projection (fp32)
    gemm_bias<<<dim3(EMB / TILE, M / TILE), dim3(256), 0, stream>>>(
        ctx, Wout, bout, out, M, EMB, EMB);
}